// Round 13
// baseline (73.341 us; speedup 1.0000x reference)
//
#include <hip/hip_runtime.h>

// Problem: N=65536 rows, H=512, E=8, OUT=2.
//   oh=x[:,0:8], delta=x[:,8], phi=x[:,9]
//   h  = relu(delta*w1 + b1 + phi*(oh@meta_w) + oh@meta_b)   -> one K=32 bf16 MFMA GEMM
//   h2 = relu(h @ w2 + b2)                                   -> main GEMM, bf16 MFMA, K=512
//   out = h2 @ w3 + b3                                       -> fused shuffle-reduce epilogue
//
// R13: halve L2 traffic. BM=128 rows/block (512 blocks x 512KB = 268MB L2 vs
// R11's 536MB). 16 waves (1024 thr), wave tile 128 rows x 32 cols in 16x16
// frags -> acc[8][2] = 16 INDEPENDENT accs (R12 proved 4 accs stall on MFMA
// dependency; R11's 16 was the winning pattern). Split-af halves + sched
// barrier (R11 recipe) keeps VALU live ~52 <= 64. h LDS = 128KB (1 block/CU,
// 4 waves/SIMD -- same TLP as R11). bf: 2 global loads/iter from L2.

#define BM 128

typedef float f32x4 __attribute__((ext_vector_type(4)));
typedef short s16x8 __attribute__((ext_vector_type(8)));

__device__ __forceinline__ short f2bf(float f) {
    union { float f; unsigned u; } c; c.f = f;
    unsigned u = c.u;
    return (short)((u + 0x7FFFu + ((u >> 16) & 1u)) >> 16);  // RNE
}

// ---------------- prep: build bf16 weight images in workspace ----------------
// w2s layout: [ks=16][g=4][n=512][j=8] bf16  (B-fragment order)
//   element (ks,g,n,j) = w2[k][n] with k = ks*32 + g*8 + j
// waugS layout: [col=512][k=32] bf16, rows of W' = [meta_w(8); meta_b(8); w1; b1; 0...]
__global__ void prep_kernel(const float* __restrict__ w1, const float* __restrict__ b1,
                            const float* __restrict__ mw, const float* __restrict__ mb,
                            const float* __restrict__ w2,
                            short* __restrict__ w2s, short* __restrict__ waugS) {
    int id = blockIdx.x * 256 + threadIdx.x;
    if (id < 512 * 512) {
        int k = id / 512, n = id % 512;
        int ks = k >> 5, g = (k >> 3) & 3, j = k & 7;
        w2s[(((ks * 4 + g) * 512) + n) * 8 + j] = f2bf(w2[id]);
    }
    if (id < 512 * 32) {
        int col = id >> 5, k = id & 31;
        float v = 0.f;
        if (k < 8)        v = mw[k * 512 + col];
        else if (k < 16)  v = mb[(k - 8) * 512 + col];
        else if (k == 16) v = w1[col];
        else if (k == 17) v = b1[col];
        waugS[col * 32 + k] = f2bf(v);
    }
}

// ---------------- fused MLP ----------------
// grid 512 blocks x 1024 threads (16 waves). Block tile: 128 rows x 512 cols.
// Wave w owns cols [w*32, w*32+32), all 128 rows -> acc 8(m) x 2(n) frags.
__global__ __launch_bounds__(1024, 4) void fused_mlp(
    const float* __restrict__ x, const short* __restrict__ waugS,
    const short* __restrict__ w2s, const float* __restrict__ b2,
    const float* __restrict__ w3, const float* __restrict__ b3,
    float* __restrict__ out) {

    // h in FRAGMENT order: short idx = (c>>3)*1024 + row*8 + (c&7)  (128 rows)
    __shared__ __align__(16) short haug[128 * 512];         // 128KB
    __shared__ float xls[128 * 10];                         // 5120 B
    __shared__ float oacc[256];                             // 1024 B

    const int tid  = threadIdx.x;
    const int wv   = tid >> 6;           // 0..15
    const int lane = tid & 63;
    const int l15  = lane & 15;
    const int g    = lane >> 4;
    const long rowbase = (long)blockIdx.x * BM;

    // ---- load x tile (128x10 f32 = 1280 floats), zero out-acc ----
    for (int i = tid; i < BM * 10; i += 1024) xls[i] = x[rowbase * 10 + i];
    if (tid < 256) oacc[tid] = 0.f;
    __syncthreads();

    // ---- layer 1: K=32 MFMA pass; h -> LDS in fragment order ----
    {
        s16x8 bfr[2];
#pragma unroll
        for (int nf = 0; nf < 2; ++nf) {
            int col = wv * 32 + nf * 16 + l15;
            bfr[nf] = *(const s16x8*)(waugS + col * 32 + g * 8);
        }
#pragma unroll
        for (int m = 0; m < 8; ++m) {
            int r = m * 16 + l15;
            float v[8];
            if (g == 0) {                    // k=0..7 : oh * phi
                float phi = xls[r * 10 + 9];
#pragma unroll
                for (int j = 0; j < 8; ++j) v[j] = xls[r * 10 + j] * phi;
            } else if (g == 1) {             // k=8..15 : oh
#pragma unroll
                for (int j = 0; j < 8; ++j) v[j] = xls[r * 10 + j];
            } else if (g == 2) {             // k=16,17 : delta, 1
                v[0] = xls[r * 10 + 8]; v[1] = 1.f;
#pragma unroll
                for (int j = 2; j < 8; ++j) v[j] = 0.f;
            } else {                         // k=24..31 : 0
#pragma unroll
                for (int j = 0; j < 8; ++j) v[j] = 0.f;
            }
            s16x8 a;
#pragma unroll
            for (int j = 0; j < 8; ++j) a[j] = f2bf(v[j]);
#pragma unroll
            for (int nf = 0; nf < 2; ++nf) {
                int col = wv * 32 + nf * 16 + l15;
                int chi = (col >> 3) * 1024 + (col & 7);
                f32x4 c = {0.f, 0.f, 0.f, 0.f};
                c = __builtin_amdgcn_mfma_f32_16x16x32_bf16(a, bfr[nf], c, 0, 0, 0);
#pragma unroll
                for (int r4 = 0; r4 < 4; ++r4) {
                    int row = m * 16 + g * 4 + r4;
                    float hv = c[r4];
                    hv = hv > 0.f ? hv : 0.f;
                    haug[chi + row * 8] = f2bf(hv);
                }
            }
        }
    }
    __syncthreads();   // h ready; haug read-only from here -> no more barriers

    // ---- layer 2: K=512 in 16 steps of 32; split-af schedule, barrier-free ----
    f32x4 acc[8][2];
#pragma unroll
    for (int m = 0; m < 8; ++m)
#pragma unroll
        for (int n = 0; n < 2; ++n) acc[m][n] = (f32x4){0.f, 0.f, 0.f, 0.f};

    // bf: byte = (t*4+g)*8192 + (wv*32 + nf*16 + l15)*16 ; per-t stride 32768B
    const char* bfp = (const char*)w2s + g * 8192 + (wv * 32 + l15) * 16;
    // af: byte = t*8192 + g*2048 + m*256 + l15*16 ; per-t stride 8192B
    const char* hbp = (const char*)haug + g * 2048 + l15 * 16;

#pragma unroll 1
    for (int t = 0; t < 16; ++t) {
        s16x8 bf0 = *(const s16x8*)(bfp);
        s16x8 bf1 = *(const s16x8*)(bfp + 256);
        s16x8 a0  = *(const s16x8*)(hbp);
        s16x8 a1  = *(const s16x8*)(hbp + 256);
        s16x8 a2  = *(const s16x8*)(hbp + 512);
        s16x8 a3  = *(const s16x8*)(hbp + 768);
        acc[0][0] = __builtin_amdgcn_mfma_f32_16x16x32_bf16(a0, bf0, acc[0][0], 0, 0, 0);
        acc[0][1] = __builtin_amdgcn_mfma_f32_16x16x32_bf16(a0, bf1, acc[0][1], 0, 0, 0);
        acc[1][0] = __builtin_amdgcn_mfma_f32_16x16x32_bf16(a1, bf0, acc[1][0], 0, 0, 0);
        acc[1][1] = __builtin_amdgcn_mfma_f32_16x16x32_bf16(a1, bf1, acc[1][1], 0, 0, 0);
        acc[2][0] = __builtin_amdgcn_mfma_f32_16x16x32_bf16(a2, bf0, acc[2][0], 0, 0, 0);
        acc[2][1] = __builtin_amdgcn_mfma_f32_16x16x32_bf16(a2, bf1, acc[2][1], 0, 0, 0);
        acc[3][0] = __builtin_amdgcn_mfma_f32_16x16x32_bf16(a3, bf0, acc[3][0], 0, 0, 0);
        acc[3][1] = __builtin_amdgcn_mfma_f32_16x16x32_bf16(a3, bf1, acc[3][1], 0, 0, 0);
        __builtin_amdgcn_sched_barrier(0);   // pin af4..7 loads here (reuse a0..a3 regs)
        s16x8 a4  = *(const s16x8*)(hbp + 1024);
        s16x8 a5  = *(const s16x8*)(hbp + 1280);
        s16x8 a6  = *(const s16x8*)(hbp + 1536);
        s16x8 a7  = *(const s16x8*)(hbp + 1792);
        acc[4][0] = __builtin_amdgcn_mfma_f32_16x16x32_bf16(a4, bf0, acc[4][0], 0, 0, 0);
        acc[4][1] = __builtin_amdgcn_mfma_f32_16x16x32_bf16(a4, bf1, acc[4][1], 0, 0, 0);
        acc[5][0] = __builtin_amdgcn_mfma_f32_16x16x32_bf16(a5, bf0, acc[5][0], 0, 0, 0);
        acc[5][1] = __builtin_amdgcn_mfma_f32_16x16x32_bf16(a5, bf1, acc[5][1], 0, 0, 0);
        acc[6][0] = __builtin_amdgcn_mfma_f32_16x16x32_bf16(a6, bf0, acc[6][0], 0, 0, 0);
        acc[6][1] = __builtin_amdgcn_mfma_f32_16x16x32_bf16(a6, bf1, acc[6][1], 0, 0, 0);
        acc[7][0] = __builtin_amdgcn_mfma_f32_16x16x32_bf16(a7, bf0, acc[7][0], 0, 0, 0);
        acc[7][1] = __builtin_amdgcn_mfma_f32_16x16x32_bf16(a7, bf1, acc[7][1], 0, 0, 0);
        bfp += 32768;
        hbp += 8192;
    }

    // ---- layer 3: relu(acc+b2) @ w3, per-(m,r4) immediate reduce ----
    float bb2[2], w30[2], w31[2];
#pragma unroll
    for (int n = 0; n < 2; ++n) {
        int col = wv * 32 + n * 16 + l15;
        bb2[n] = b2[col];
        w30[n] = w3[col * 2 + 0];
        w31[n] = w3[col * 2 + 1];
    }
#pragma unroll
    for (int m = 0; m < 8; ++m) {
#pragma unroll
        for (int r4 = 0; r4 < 4; ++r4) {
            float s0 = 0.f, s1 = 0.f;
#pragma unroll
            for (int n = 0; n < 2; ++n) {
                float v = acc[m][n][r4] + bb2[n];
                v = v > 0.f ? v : 0.f;
                s0 += v * w30[n];
                s1 += v * w31[n];
            }
            s0 += __shfl_xor(s0, 1); s1 += __shfl_xor(s1, 1);
            s0 += __shfl_xor(s0, 2); s1 += __shfl_xor(s1, 2);
            s0 += __shfl_xor(s0, 4); s1 += __shfl_xor(s1, 4);
            s0 += __shfl_xor(s0, 8); s1 += __shfl_xor(s1, 8);
            if (l15 == 0) {
                int row = m * 16 + g * 4 + r4;
                atomicAdd(&oacc[row * 2 + 0], s0);
                atomicAdd(&oacc[row * 2 + 1], s1);
            }
        }
    }
    __syncthreads();

    if (tid < 256) {
        int row = tid >> 1, o = tid & 1;
        out[(rowbase + row) * 2 + o] = oacc[tid] + b3[o];
    }
}

extern "C" void kernel_launch(void* const* d_in, const int* in_sizes, int n_in,
                              void* d_out, int out_size, void* d_ws, size_t ws_size,
                              hipStream_t stream) {
    const float* x  = (const float*)d_in[0];
    const float* w1 = (const float*)d_in[1];
    const float* b1 = (const float*)d_in[2];
    const float* mw = (const float*)d_in[3];
    const float* mb = (const float*)d_in[4];
    const float* w2 = (const float*)d_in[5];
    const float* b2 = (const float*)d_in[6];
    const float* w3 = (const float*)d_in[7];
    const float* b3 = (const float*)d_in[8];
    float* out = (float*)d_out;

    short* w2s   = (short*)d_ws;          // 512 KB
    short* waugS = w2s + 512 * 512;       // 32 KB

    prep_kernel<<<1024, 256, 0, stream>>>(w1, b1, mw, mb, w2, w2s, waugS);
    fused_mlp<<<65536 / BM, 1024, 0, stream>>>(x, waugS, w2s, b2, w3, b3, out);
}

// Round 14
// 57.657 us; speedup vs baseline: 1.2720x; 1.2720x over previous
//
#include <hip/hip_runtime.h>

// Problem: N=65536 rows, H=512, E=8, OUT=2.
//   oh=x[:,0:8], delta=x[:,8], phi=x[:,9]
//   h  = relu(delta*w1 + b1 + phi*(oh@meta_w) + oh@meta_b)   -> one K=32 bf16 MFMA GEMM
//   h2 = relu(h @ w2 + b2)                                   -> main GEMM, bf16 MFMA, K=512
//   out = h2 @ w3 + b3                                       -> fused shuffle-reduce epilogue
//
// R14 = R11 MFMA body + R12 prefetch skeleton:
//   - 16 INDEPENDENT 16x16 accs (acc[4][4]) -- R12 proved 4 accs dependent-stall
//   - ping-pong 1-deep bf prefetch (bfA/bfB), #pragma unroll 1, peeled tail
//     -- R11 proved no-prefetch leaves ~400cy L2 latency exposed (MLP-bound:
//        536MB/55us = 9.7TB/s = 30% of L2 ceiling; only 4KB in flight/wave)
//   - regs: acc 64 AGPR + bfA 16 + bfB 16 + af 16 + addr ~8 < 128 unified cap
//     at __launch_bounds__(512,4): 2 blocks/CU, 4 waves/SIMD, zero spill.

#define BM 64

typedef float f32x4 __attribute__((ext_vector_type(4)));
typedef short s16x8 __attribute__((ext_vector_type(8)));

__device__ __forceinline__ short f2bf(float f) {
    union { float f; unsigned u; } c; c.f = f;
    unsigned u = c.u;
    return (short)((u + 0x7FFFu + ((u >> 16) & 1u)) >> 16);  // RNE
}

// ---------------- prep: build bf16 weight images in workspace ----------------
// w2s layout: [ks=16][g=4][n=512][j=8] bf16  (B-fragment order)
//   element (ks,g,n,j) = w2[k][n] with k = ks*32 + g*8 + j
// waugS layout: [col=512][k=32] bf16, rows of W' = [meta_w(8); meta_b(8); w1; b1; 0...]
__global__ void prep_kernel(const float* __restrict__ w1, const float* __restrict__ b1,
                            const float* __restrict__ mw, const float* __restrict__ mb,
                            const float* __restrict__ w2,
                            short* __restrict__ w2s, short* __restrict__ waugS) {
    int id = blockIdx.x * 256 + threadIdx.x;
    if (id < 512 * 512) {
        int k = id / 512, n = id % 512;
        int ks = k >> 5, g = (k >> 3) & 3, j = k & 7;
        w2s[(((ks * 4 + g) * 512) + n) * 8 + j] = f2bf(w2[id]);
    }
    if (id < 512 * 32) {
        int col = id >> 5, k = id & 31;
        float v = 0.f;
        if (k < 8)        v = mw[k * 512 + col];
        else if (k < 16)  v = mb[(k - 8) * 512 + col];
        else if (k == 16) v = w1[col];
        else if (k == 17) v = b1[col];
        waugS[col * 32 + k] = f2bf(v);
    }
}

// ---------------- fused MLP ----------------
// grid 1024 blocks x 512 threads (8 waves). Block tile: 64 rows x 512 cols.
// Wave w owns cols [w*64, w*64+64), all 64 rows -> acc 4(m) x 4(n) frags.
__global__ __launch_bounds__(512, 4) void fused_mlp(
    const float* __restrict__ x, const short* __restrict__ waugS,
    const short* __restrict__ w2s, const float* __restrict__ b2,
    const float* __restrict__ w3, const float* __restrict__ b3,
    float* __restrict__ out) {

    // h in FRAGMENT order: short idx = (k>>3)*512 + row*8 + (k&7)
    __shared__ __align__(16) short haug[64 * 512];          // 64KB
    __shared__ float xls[64 * 10];                          // 2560 B
    __shared__ float oacc[128];                             // 512 B

    const int tid  = threadIdx.x;
    const int wv   = tid >> 6;           // 0..7
    const int lane = tid & 63;
    const int l15  = lane & 15;
    const int g    = lane >> 4;
    const long rowbase = (long)blockIdx.x * BM;

    // ---- load x tile (64x10 f32 = 640 floats, strided over 512 thr), zero out-acc ----
    for (int i = tid; i < BM * 10; i += 512) xls[i] = x[rowbase * 10 + i];
    if (tid < 128) oacc[tid] = 0.f;
    __syncthreads();

    // ---- layer 1: one K=32 MFMA pass; h -> LDS in fragment order ----
    {
        s16x8 afr[4];
#pragma unroll
        for (int m = 0; m < 4; ++m) {
            int r = m * 16 + l15;
            float v[8];
            if (g == 0) {                    // k=0..7 : oh * phi
                float phi = xls[r * 10 + 9];
#pragma unroll
                for (int j = 0; j < 8; ++j) v[j] = xls[r * 10 + j] * phi;
            } else if (g == 1) {             // k=8..15 : oh
#pragma unroll
                for (int j = 0; j < 8; ++j) v[j] = xls[r * 10 + j];
            } else if (g == 2) {             // k=16,17 : delta, 1
                v[0] = xls[r * 10 + 8]; v[1] = 1.f;
#pragma unroll
                for (int j = 2; j < 8; ++j) v[j] = 0.f;
            } else {                         // k=24..31 : 0
#pragma unroll
                for (int j = 0; j < 8; ++j) v[j] = 0.f;
            }
            s16x8 a;
#pragma unroll
            for (int j = 0; j < 8; ++j) a[j] = f2bf(v[j]);
            afr[m] = a;
        }
#pragma unroll
        for (int nf = 0; nf < 4; ++nf) {
            int col = wv * 64 + nf * 16 + l15;
            s16x8 bfr = *(const s16x8*)(waugS + col * 32 + g * 8);
            int chi = (col >> 3) * 512 + (col & 7);          // fragment-order column part
#pragma unroll
            for (int m = 0; m < 4; ++m) {
                f32x4 c = {0.f, 0.f, 0.f, 0.f};
                c = __builtin_amdgcn_mfma_f32_16x16x32_bf16(afr[m], bfr, c, 0, 0, 0);
#pragma unroll
                for (int r4 = 0; r4 < 4; ++r4) {
                    int row = m * 16 + g * 4 + r4;
                    float hv = c[r4];
                    hv = hv > 0.f ? hv : 0.f;
                    haug[chi + row * 8] = f2bf(hv);
                }
            }
        }
    }
    __syncthreads();   // h ready; haug read-only from here -> no more barriers

    // ---- layer 2: K=512 in 16 steps of 32; 16 indep accs + ping-pong bf prefetch ----
    f32x4 acc[4][4];
#pragma unroll
    for (int m = 0; m < 4; ++m)
#pragma unroll
        for (int n = 0; n < 4; ++n) acc[m][n] = (f32x4){0.f, 0.f, 0.f, 0.f};

    // bf: byte = t*32768 + g*8192 + (wv*64+l15)*16 + n*256
    const char* bfp = (const char*)w2s + g * 8192 + (wv * 64 + l15) * 16;
    // af: byte = t*4096 + g*1024 + m*256 + l15*16
    const char* hbp = (const char*)haug + g * 1024 + l15 * 16;

#define LOADB(dst, T)                                                  \
    do {                                                               \
        dst[0] = *(const s16x8*)(bfp + (size_t)(T) * 32768);           \
        dst[1] = *(const s16x8*)(bfp + (size_t)(T) * 32768 + 256);     \
        dst[2] = *(const s16x8*)(bfp + (size_t)(T) * 32768 + 512);     \
        dst[3] = *(const s16x8*)(bfp + (size_t)(T) * 32768 + 768);     \
    } while (0)

#define DOSTEP(bfv)                                                                          \
    do {                                                                                     \
        s16x8 a0 = *(const s16x8*)(hbp);                                                     \
        s16x8 a1 = *(const s16x8*)(hbp + 256);                                               \
        s16x8 a2 = *(const s16x8*)(hbp + 512);                                               \
        s16x8 a3 = *(const s16x8*)(hbp + 768);                                               \
        acc[0][0] = __builtin_amdgcn_mfma_f32_16x16x32_bf16(a0, bfv[0], acc[0][0], 0, 0, 0); \
        acc[0][1] = __builtin_amdgcn_mfma_f32_16x16x32_bf16(a0, bfv[1], acc[0][1], 0, 0, 0); \
        acc[0][2] = __builtin_amdgcn_mfma_f32_16x16x32_bf16(a0, bfv[2], acc[0][2], 0, 0, 0); \
        acc[0][3] = __builtin_amdgcn_mfma_f32_16x16x32_bf16(a0, bfv[3], acc[0][3], 0, 0, 0); \
        acc[1][0] = __builtin_amdgcn_mfma_f32_16x16x32_bf16(a1, bfv[0], acc[1][0], 0, 0, 0); \
        acc[1][1] = __builtin_amdgcn_mfma_f32_16x16x32_bf16(a1, bfv[1], acc[1][1], 0, 0, 0); \
        acc[1][2] = __builtin_amdgcn_mfma_f32_16x16x32_bf16(a1, bfv[2], acc[1][2], 0, 0, 0); \
        acc[1][3] = __builtin_amdgcn_mfma_f32_16x16x32_bf16(a1, bfv[3], acc[1][3], 0, 0, 0); \
        acc[2][0] = __builtin_amdgcn_mfma_f32_16x16x32_bf16(a2, bfv[0], acc[2][0], 0, 0, 0); \
        acc[2][1] = __builtin_amdgcn_mfma_f32_16x16x32_bf16(a2, bfv[1], acc[2][1], 0, 0, 0); \
        acc[2][2] = __builtin_amdgcn_mfma_f32_16x16x32_bf16(a2, bfv[2], acc[2][2], 0, 0, 0); \
        acc[2][3] = __builtin_amdgcn_mfma_f32_16x16x32_bf16(a2, bfv[3], acc[2][3], 0, 0, 0); \
        acc[3][0] = __builtin_amdgcn_mfma_f32_16x16x32_bf16(a3, bfv[0], acc[3][0], 0, 0, 0); \
        acc[3][1] = __builtin_amdgcn_mfma_f32_16x16x32_bf16(a3, bfv[1], acc[3][1], 0, 0, 0); \
        acc[3][2] = __builtin_amdgcn_mfma_f32_16x16x32_bf16(a3, bfv[2], acc[3][2], 0, 0, 0); \
        acc[3][3] = __builtin_amdgcn_mfma_f32_16x16x32_bf16(a3, bfv[3], acc[3][3], 0, 0, 0); \
        hbp += 4096;                                                                         \
    } while (0)

    s16x8 bfA[4], bfB[4];
    LOADB(bfA, 0);                            // t=0

#pragma unroll 1
    for (int tt = 0; tt < 7; ++tt) {
        LOADB(bfB, 2 * tt + 1);               // prefetch odd t
        DOSTEP(bfA);                          // consume t = 2tt
        LOADB(bfA, 2 * tt + 2);               // prefetch next even t
        DOSTEP(bfB);                          // consume t = 2tt+1
    }
    LOADB(bfB, 15);                           // last slice
    DOSTEP(bfA);                              // t=14
    DOSTEP(bfB);                              // t=15

#undef LOADB
#undef DOSTEP

    // ---- layer 3: relu(acc+b2) @ w3, per-(m,r4) immediate reduce ----
    float bb2[4], w30[4], w31[4];
#pragma unroll
    for (int n = 0; n < 4; ++n) {
        int col = wv * 64 + n * 16 + l15;
        bb2[n] = b2[col];
        w30[n] = w3[col * 2 + 0];
        w31[n] = w3[col * 2 + 1];
    }
#pragma unroll
    for (int m = 0; m < 4; ++m) {
#pragma unroll
        for (int r4 = 0; r4 < 4; ++r4) {
            float s0 = 0.f, s1 = 0.f;
#pragma unroll
            for (int n = 0; n < 4; ++n) {
                float v = acc[m][n][r4] + bb2[n];
                v = v > 0.f ? v : 0.f;
                s0 += v * w30[n];
                s1 += v * w31[n];
            }
            s0 += __shfl_xor(s0, 1); s1 += __shfl_xor(s1, 1);
            s0 += __shfl_xor(s0, 2); s1 += __shfl_xor(s1, 2);
            s0 += __shfl_xor(s0, 4); s1 += __shfl_xor(s1, 4);
            s0 += __shfl_xor(s0, 8); s1 += __shfl_xor(s1, 8);
            if (l15 == 0) {
                int row = m * 16 + g * 4 + r4;
                atomicAdd(&oacc[row * 2 + 0], s0);
                atomicAdd(&oacc[row * 2 + 1], s1);
            }
        }
    }
    __syncthreads();

    if (tid < 128) {
        int row = tid >> 1, o = tid & 1;
        out[(rowbase + row) * 2 + o] = oacc[tid] + b3[o];
    }
}

extern "C" void kernel_launch(void* const* d_in, const int* in_sizes, int n_in,
                              void* d_out, int out_size, void* d_ws, size_t ws_size,
                              hipStream_t stream) {
    const float* x  = (const float*)d_in[0];
    const float* w1 = (const float*)d_in[1];
    const float* b1 = (const float*)d_in[2];
    const float* mw = (const float*)d_in[3];
    const float* mb = (const float*)d_in[4];
    const float* w2 = (const float*)d_in[5];
    const float* b2 = (const float*)d_in[6];
    const float* w3 = (const float*)d_in[7];
    const float* b3 = (const float*)d_in[8];
    float* out = (float*)d_out;

    short* w2s   = (short*)d_ws;          // 512 KB
    short* waugS = w2s + 512 * 512;       // 32 KB

    prep_kernel<<<1024, 256, 0, stream>>>(w1, b1, mw, mb, w2, w2s, waugS);
    fused_mlp<<<65536 / BM, 512, 0, stream>>>(x, waugS, w2s, b2, w3, b3, out);
}